// Round 5
// baseline (83.534 us; speedup 1.0000x reference)
//
#include <hip/hip_runtime.h>

// HFOnlyAttn MFMA v3: deep-MLP restructure.
// All global loads (48 X + 48 residual) issued up-front; residual folded with
// rv*bias at arrival; epilogue is pure MFMA+store. Weight frags pre-packed in
// d_ws by pack_weights. LDS = per-wave y-relayout only (6KB/wave).
// mfma_f32_16x16x32_bf16:  A: lane l -> row=l&15, k=(l>>4)*8+{0..7}
//                          B: lane l -> col=l&15, k=(l>>4)*8+{0..7}
//                          C: lane l -> col=l&15, row=(l>>4)*4+reg

typedef __attribute__((ext_vector_type(8))) short bf16x8;
typedef __attribute__((ext_vector_type(4))) float f32x4;

constexpr int kHW = 16384;
constexpr int kC = 192;

__device__ __forceinline__ unsigned short f2bf(float f) {
  unsigned int u = __float_as_uint(f);
  return (unsigned short)((u + 0x7fffu + ((u >> 16) & 1u)) >> 16);  // RNE
}

// kernel0: pack Wqkv^T/Wproj^T A-fragments into ws (24 + 8 frags x 1024B).
__global__ void pack_weights(const float* __restrict__ Wqkv,
                             const float* __restrict__ Wproj,
                             unsigned char* __restrict__ wsc) {
  const int tid = threadIdx.x;
  const int wid = tid >> 6;
  const int l = tid & 63;
  const int c = l & 15;
  const int g = l >> 4;
  for (int f = wid; f < 24; f += 4) {
    const int m = f >> 1, s = f & 1;
    const int row = m * 16 + c;
    const int k0 = s * 32 + g * 8;
    bf16x8 wf;
#pragma unroll
    for (int j = 0; j < 8; ++j) wf[j] = (short)f2bf(Wqkv[(k0 + j) * 192 + row]);
    *(bf16x8*)(wsc + f * 1024 + l * 16) = wf;
  }
  for (int f = wid; f < 8; f += 4) {
    const int m = f >> 1, s = f & 1;
    const int row = m * 16 + c;
    const int k0 = s * 32 + g * 8;
    bf16x8 wf;
#pragma unroll
    for (int j = 0; j < 8; ++j) wf[j] = (short)f2bf(Wproj[(k0 + j) * 64 + row]);
    *(bf16x8*)(wsc + 24576 + f * 1024 + l * 16) = wf;
  }
}

__global__ __launch_bounds__(256, 3) void hfattn_mfma3(
    const float* __restrict__ hf,
    const unsigned char* __restrict__ wfr,  // packed weight frags (32KB)
    const float* __restrict__ bproj,
    const float* __restrict__ rscale,
    float* __restrict__ out) {
  __shared__ char smem[24576];  // y relayout, 6KB per wave (private, no barrier)

  const int tid = threadIdx.x;
  const int wid = tid >> 6;
  const int l = tid & 63;
  const int c = l & 15;  // MFMA col (pixel slot)
  const int g = l >> 4;  // 4-lane group

  char* const yBase = smem + wid * 6144;
  const f32x4 zz = {0.f, 0.f, 0.f, 0.f};
  const bf16x8* const wp = (const bf16x8*)wfr;  // frag f, lane l -> wp[f*64+l]

  const int pxB = blockIdx.x * 64 + wid * 16;  // 2048 blocks x 64 px
  const int b8 = pxB >> 14;
  const int blkBase = b8 * (kC * kHW);
  const int hw = (pxB & (kHW - 1)) + c;
  const float* __restrict__ hfp = hf + blkBase + hw;
  float* __restrict__ outp = out + blkBase + hw;

  const float rv = rscale[0];

  // ---------- phase 1: issue ALL X loads (48 outstanding) ----------
  float xr[3][2][8];
#pragma unroll
  for (int b = 0; b < 3; ++b)
#pragma unroll
    for (int s = 0; s < 2; ++s)
#pragma unroll
      for (int j = 0; j < 8; ++j)
        xr[b][s][j] = hfp[(b * 64 + s * 32 + g * 8 + j) * kHW];

  // ---------- phase 2: residual loads (hide under the whole head loop) ----------
  float res[3][4][4];
#pragma unroll
  for (int b = 0; b < 3; ++b)
#pragma unroll
    for (int m = 0; m < 4; ++m)
#pragma unroll
      for (int j = 0; j < 4; ++j)
        res[b][m][j] = hfp[(b * 64 + m * 16 + g * 4 + j) * kHW];

  // fold rv*bias into res (rvb regs die after this)
  {
#pragma unroll
    for (int m = 0; m < 4; ++m) {
      const float4 bj = *(const float4*)(bproj + m * 16 + g * 4);
      const float rb0 = rv * bj.x, rb1 = rv * bj.y, rb2 = rv * bj.z,
                  rb3 = rv * bj.w;
#pragma unroll
      for (int b = 0; b < 3; ++b) {
        res[b][m][0] += rb0;
        res[b][m][1] += rb1;
        res[b][m][2] += rb2;
        res[b][m][3] += rb3;
      }
    }
  }

  // ---------- convert X to bf16 fragments ----------
  bf16x8 Xf[3][2];
#pragma unroll
  for (int b = 0; b < 3; ++b)
#pragma unroll
    for (int s = 0; s < 2; ++s) {
      bf16x8 xf;
#pragma unroll
      for (int j = 0; j < 8; ++j) xf[j] = (short)f2bf(xr[b][s][j]);
      Xf[b][s] = xf;
    }

  // ---------- per-head: q,k -> softmax -> v -> y -> LDS ----------
#pragma unroll 1
  for (int h = 0; h < 4; ++h) {
    const bf16x8 qA0 = wp[(h * 2 + 0) * 64 + l];
    const bf16x8 qA1 = wp[(h * 2 + 1) * 64 + l];
    const bf16x8 kA0 = wp[((4 + h) * 2 + 0) * 64 + l];
    const bf16x8 kA1 = wp[((4 + h) * 2 + 1) * 64 + l];
    f32x4 q[3], k[3];
#pragma unroll
    for (int b = 0; b < 3; ++b) {
      q[b] = __builtin_amdgcn_mfma_f32_16x16x32_bf16(qA0, Xf[b][0], zz, 0, 0, 0);
      q[b] = __builtin_amdgcn_mfma_f32_16x16x32_bf16(qA1, Xf[b][1], q[b], 0, 0, 0);
      k[b] = __builtin_amdgcn_mfma_f32_16x16x32_bf16(kA0, Xf[b][0], zz, 0, 0, 0);
      k[b] = __builtin_amdgcn_mfma_f32_16x16x32_bf16(kA1, Xf[b][1], k[b], 0, 0, 0);
    }
    // scores + softmax (reduce over the 4-lane row-groups)
    float P[3][3];
#pragma unroll
    for (int r1 = 0; r1 < 3; ++r1) {
      float sc[3];
#pragma unroll
      for (int r2 = 0; r2 < 3; ++r2) {
        float d = q[r1][0] * k[r2][0] + q[r1][1] * k[r2][1] +
                  q[r1][2] * k[r2][2] + q[r1][3] * k[r2][3];
        d += __shfl_xor(d, 16);
        d += __shfl_xor(d, 32);
        sc[r2] = d * 0.25f;
      }
      const float mx = fmaxf(sc[0], fmaxf(sc[1], sc[2]));
      const float e0 = __expf(sc[0] - mx);
      const float e1 = __expf(sc[1] - mx);
      const float e2 = __expf(sc[2] - mx);
      const float inv = 1.f / (e0 + e1 + e2);
      P[r1][0] = e0 * inv;
      P[r1][1] = e1 * inv;
      P[r1][2] = e2 * inv;
    }
    // v
    const bf16x8 vA0 = wp[((8 + h) * 2 + 0) * 64 + l];
    const bf16x8 vA1 = wp[((8 + h) * 2 + 1) * 64 + l];
    f32x4 v[3];
#pragma unroll
    for (int b = 0; b < 3; ++b) {
      v[b] = __builtin_amdgcn_mfma_f32_16x16x32_bf16(vA0, Xf[b][0], zz, 0, 0, 0);
      v[b] = __builtin_amdgcn_mfma_f32_16x16x32_bf16(vA1, Xf[b][1], v[b], 0, 0, 0);
    }
    // y = P @ v -> LDS in proj-B-frag layout
    const int sp = h >> 1;
    const int gp = (h & 1) * 2 + (g >> 1);
    const int wslot = (gp * 16 + c) * 16 + (g & 1) * 8;
#pragma unroll
    for (int r1 = 0; r1 < 3; ++r1) {
      float y0 = P[r1][0] * v[0][0] + P[r1][1] * v[1][0] + P[r1][2] * v[2][0];
      float y1 = P[r1][0] * v[0][1] + P[r1][1] * v[1][1] + P[r1][2] * v[2][1];
      float y2 = P[r1][0] * v[0][2] + P[r1][1] * v[1][2] + P[r1][2] * v[2][2];
      float y3 = P[r1][0] * v[0][3] + P[r1][1] * v[1][3] + P[r1][2] * v[2][3];
      uint2 pk;
      pk.x = (unsigned)f2bf(y0) | ((unsigned)f2bf(y1) << 16);
      pk.y = (unsigned)f2bf(y2) | ((unsigned)f2bf(y3) << 16);
      *(uint2*)(yBase + (r1 * 2 + sp) * 1024 + wslot) = pk;
    }
  }

  // ---------- epilogue: proj + residual, fully hoisted ----------
  bf16x8 yB[3][2];
#pragma unroll
  for (int b = 0; b < 3; ++b)
#pragma unroll
    for (int s = 0; s < 2; ++s)
      yB[b][s] = *(bf16x8*)(yBase + (b * 2 + s) * 1024 + l * 16);

  bf16x8 pA[4][2];
#pragma unroll
  for (int m = 0; m < 4; ++m)
#pragma unroll
    for (int s = 0; s < 2; ++s) pA[m][s] = wp[(24 + m * 2 + s) * 64 + l];

#pragma unroll
  for (int b = 0; b < 3; ++b) {
#pragma unroll
    for (int m = 0; m < 4; ++m) {
      f32x4 o =
          __builtin_amdgcn_mfma_f32_16x16x32_bf16(pA[m][0], yB[b][0], zz, 0, 0, 0);
      o = __builtin_amdgcn_mfma_f32_16x16x32_bf16(pA[m][1], yB[b][1], o, 0, 0, 0);
#pragma unroll
      for (int j = 0; j < 4; ++j) {
        outp[(b * 64 + m * 16 + g * 4 + j) * kHW] =
            fmaf(rv, o[j], res[b][m][j]);
      }
    }
  }
}

extern "C" void kernel_launch(void* const* d_in, const int* in_sizes, int n_in,
                              void* d_out, int out_size, void* d_ws,
                              size_t ws_size, hipStream_t stream) {
  const float* hf = (const float*)d_in[0];
  const float* Wqkv = (const float*)d_in[1];
  const float* Wproj = (const float*)d_in[2];
  const float* bproj = (const float*)d_in[3];
  const float* rscale = (const float*)d_in[4];
  float* out = (float*)d_out;
  unsigned char* wsc = (unsigned char*)d_ws;

  hipLaunchKernelGGL(pack_weights, dim3(1), dim3(256), 0, stream, Wqkv, Wproj,
                     wsc);

  const int npix = in_sizes[0] / kC;  // 131072
  const int nblocks = npix / 64;      // 2048
  hipLaunchKernelGGL(hfattn_mfma3, dim3(nblocks), dim3(256), 0, stream, hf, wsc,
                     bproj, rscale, out);
}

// Round 6
// 71.125 us; speedup vs baseline: 1.1745x; 1.1745x over previous
//
#include <hip/hip_runtime.h>

// HFOnlyAttn MFMA v4: v2 structure, but y-relayout done via ds_bpermute
// (shuffles) instead of LDS -> zero LDS, zero barriers, occupancy by VGPR only.
// qkv^T = Wqkv^T (192x64) @ X^T (64 x px); 4-head 3x3 softmax in-register;
// y relayout in-register via shuffles; out^T = Wproj^T @ y^T; residual epilogue.
// mfma_f32_16x16x32_bf16:  A: lane l -> row=l&15, k=(l>>4)*8+{0..7}
//                          B: lane l -> col=l&15, k=(l>>4)*8+{0..7}
//                          C: lane l -> col=l&15, row=(l>>4)*4+reg
// Relayout math (verified): proj-B-frag(sp) lane(g,c) element e = ych
// sp*32+g*8+e; holder = lane ((g&1)*2 + (e>>2))*16 + c, head sp*2+(g>>1),
// reg e&3.  (g>>1)*16+(g&1)*8 == g*8.

typedef __attribute__((ext_vector_type(8))) short bf16x8;
typedef __attribute__((ext_vector_type(4))) float f32x4;

constexpr int kHW = 16384;
constexpr int kC = 192;

__device__ __forceinline__ unsigned short f2bf(float f) {
  unsigned int u = __float_as_uint(f);
  return (unsigned short)((u + 0x7fffu + ((u >> 16) & 1u)) >> 16);  // RNE
}

// kernel0: pack Wqkv^T/Wproj^T A-fragments into ws (24 + 8 frags x 1024B).
__global__ void pack_weights(const float* __restrict__ Wqkv,
                             const float* __restrict__ Wproj,
                             unsigned char* __restrict__ wsc) {
  const int tid = threadIdx.x;
  const int wid = tid >> 6;
  const int l = tid & 63;
  const int c = l & 15;
  const int g = l >> 4;
  for (int f = wid; f < 24; f += 4) {
    const int m = f >> 1, s = f & 1;
    const int row = m * 16 + c;
    const int k0 = s * 32 + g * 8;
    bf16x8 wf;
#pragma unroll
    for (int j = 0; j < 8; ++j) wf[j] = (short)f2bf(Wqkv[(k0 + j) * 192 + row]);
    *(bf16x8*)(wsc + f * 1024 + l * 16) = wf;
  }
  for (int f = wid; f < 8; f += 4) {
    const int m = f >> 1, s = f & 1;
    const int row = m * 16 + c;
    const int k0 = s * 32 + g * 8;
    bf16x8 wf;
#pragma unroll
    for (int j = 0; j < 8; ++j) wf[j] = (short)f2bf(Wproj[(k0 + j) * 64 + row]);
    *(bf16x8*)(wsc + 24576 + f * 1024 + l * 16) = wf;
  }
}

// One head: q,k MFMAs -> 3x3 softmax -> v MFMAs -> y packs (3 uint2).
template <int H>
__device__ __forceinline__ void head_compute(const bf16x8* __restrict__ wp,
                                             int l, const bf16x8 (&Xf)[3][2],
                                             uint2 (&pk)[3]) {
  const f32x4 zz = {0.f, 0.f, 0.f, 0.f};
  const bf16x8 qA0 = wp[(H * 2 + 0) * 64 + l];
  const bf16x8 qA1 = wp[(H * 2 + 1) * 64 + l];
  const bf16x8 kA0 = wp[((4 + H) * 2 + 0) * 64 + l];
  const bf16x8 kA1 = wp[((4 + H) * 2 + 1) * 64 + l];
  f32x4 q[3], k[3];
#pragma unroll
  for (int b = 0; b < 3; ++b) {
    q[b] = __builtin_amdgcn_mfma_f32_16x16x32_bf16(qA0, Xf[b][0], zz, 0, 0, 0);
    q[b] = __builtin_amdgcn_mfma_f32_16x16x32_bf16(qA1, Xf[b][1], q[b], 0, 0, 0);
    k[b] = __builtin_amdgcn_mfma_f32_16x16x32_bf16(kA0, Xf[b][0], zz, 0, 0, 0);
    k[b] = __builtin_amdgcn_mfma_f32_16x16x32_bf16(kA1, Xf[b][1], k[b], 0, 0, 0);
  }
  float P[3][3];
#pragma unroll
  for (int r1 = 0; r1 < 3; ++r1) {
    float sc[3];
#pragma unroll
    for (int r2 = 0; r2 < 3; ++r2) {
      float d = q[r1][0] * k[r2][0] + q[r1][1] * k[r2][1] +
                q[r1][2] * k[r2][2] + q[r1][3] * k[r2][3];
      d += __shfl_xor(d, 16);
      d += __shfl_xor(d, 32);
      sc[r2] = d * 0.25f;
    }
    const float mx = fmaxf(sc[0], fmaxf(sc[1], sc[2]));
    const float e0 = __expf(sc[0] - mx);
    const float e1 = __expf(sc[1] - mx);
    const float e2 = __expf(sc[2] - mx);
    const float inv = 1.f / (e0 + e1 + e2);
    P[r1][0] = e0 * inv;
    P[r1][1] = e1 * inv;
    P[r1][2] = e2 * inv;
  }
  const bf16x8 vA0 = wp[((8 + H) * 2 + 0) * 64 + l];
  const bf16x8 vA1 = wp[((8 + H) * 2 + 1) * 64 + l];
  f32x4 v[3];
#pragma unroll
  for (int b = 0; b < 3; ++b) {
    v[b] = __builtin_amdgcn_mfma_f32_16x16x32_bf16(vA0, Xf[b][0], zz, 0, 0, 0);
    v[b] = __builtin_amdgcn_mfma_f32_16x16x32_bf16(vA1, Xf[b][1], v[b], 0, 0, 0);
  }
#pragma unroll
  for (int r1 = 0; r1 < 3; ++r1) {
    f32x4 y = P[r1][0] * v[0] + P[r1][1] * v[1] + P[r1][2] * v[2];
    uint2 p;
    p.x = (unsigned)f2bf(y[0]) | ((unsigned)f2bf(y[1]) << 16);
    p.y = (unsigned)f2bf(y[2]) | ((unsigned)f2bf(y[3]) << 16);
    pk[r1] = p;
  }
}

// Build proj-B-frag for K-step sp from the packs of heads (2sp, 2sp+1).
__device__ __forceinline__ bf16x8 build_frag(uint2 pkA, uint2 pkB, int srcA,
                                             bool hi) {
  uint2 a0, a1, b0, b1;
  a0.x = (unsigned)__shfl((int)pkA.x, srcA, 64);
  a0.y = (unsigned)__shfl((int)pkA.y, srcA, 64);
  a1.x = (unsigned)__shfl((int)pkB.x, srcA, 64);
  a1.y = (unsigned)__shfl((int)pkB.y, srcA, 64);
  const int srcB = srcA + 16;
  b0.x = (unsigned)__shfl((int)pkA.x, srcB, 64);
  b0.y = (unsigned)__shfl((int)pkA.y, srcB, 64);
  b1.x = (unsigned)__shfl((int)pkB.x, srcB, 64);
  b1.y = (unsigned)__shfl((int)pkB.y, srcB, 64);
  const uint2 lo = hi ? a1 : a0;
  const uint2 hi2 = hi ? b1 : b0;
  union {
    unsigned u[4];
    bf16x8 v;
  } r;
  r.u[0] = lo.x;
  r.u[1] = lo.y;
  r.u[2] = hi2.x;
  r.u[3] = hi2.y;
  return r.v;
}

__global__ __launch_bounds__(256, 4) void hfattn_mfma4(
    const float* __restrict__ hf,
    const unsigned char* __restrict__ wfr,  // packed weight frags (32KB)
    const float* __restrict__ bproj,
    const float* __restrict__ rscale,
    float* __restrict__ out) {
  const int tid = threadIdx.x;
  const int wid = tid >> 6;
  const int l = tid & 63;
  const int c = l & 15;  // MFMA col (pixel slot)
  const int g = l >> 4;  // 4-lane group

  const f32x4 zz = {0.f, 0.f, 0.f, 0.f};
  const bf16x8* const wp = (const bf16x8*)wfr;

  const int pxB = blockIdx.x * 64 + wid * 16;  // 2048 blocks x 64 px
  const int b8 = pxB >> 14;
  const int blkBase = b8 * (kC * kHW);
  const int hw = (pxB & (kHW - 1)) + c;
  const float* __restrict__ hfp = hf + blkBase + hw;
  float* __restrict__ outp = out + blkBase + hw;

  const float rv = rscale[0];

  // ---------- X fragments from global ----------
  bf16x8 Xf[3][2];
#pragma unroll
  for (int b = 0; b < 3; ++b)
#pragma unroll
    for (int s = 0; s < 2; ++s) {
      const int ch0 = b * 64 + s * 32 + g * 8;
      float xr[8];
#pragma unroll
      for (int j = 0; j < 8; ++j) xr[j] = hfp[(ch0 + j) * kHW];
      bf16x8 xf;
#pragma unroll
      for (int j = 0; j < 8; ++j) xf[j] = (short)f2bf(xr[j]);
      Xf[b][s] = xf;
    }

  // ---------- heads + in-register relayout ----------
  const int srcA = ((g & 1) * 2) * 16 + c;
  const bool hi = (g >> 1) & 1;

  uint2 pkA[3], pkB[3];
  bf16x8 yS0[3], yS1[3];

  head_compute<0>(wp, l, Xf, pkA);
  __builtin_amdgcn_sched_barrier(0);
  head_compute<1>(wp, l, Xf, pkB);
  __builtin_amdgcn_sched_barrier(0);
#pragma unroll
  for (int b = 0; b < 3; ++b) yS0[b] = build_frag(pkA[b], pkB[b], srcA, hi);
  __builtin_amdgcn_sched_barrier(0);
  head_compute<2>(wp, l, Xf, pkA);
  __builtin_amdgcn_sched_barrier(0);
  head_compute<3>(wp, l, Xf, pkB);
  __builtin_amdgcn_sched_barrier(0);
#pragma unroll
  for (int b = 0; b < 3; ++b) yS1[b] = build_frag(pkA[b], pkB[b], srcA, hi);

  // ---------- bias ----------
  float bias_[4][4];
#pragma unroll
  for (int m = 0; m < 4; ++m) {
    const float4 bj = *(const float4*)(bproj + m * 16 + g * 4);
    bias_[m][0] = bj.x;
    bias_[m][1] = bj.y;
    bias_[m][2] = bj.z;
    bias_[m][3] = bj.w;
  }

  // ---------- epilogue: proj + residual ----------
#pragma unroll
  for (int b = 0; b < 3; ++b) {
    float res[4][4];
#pragma unroll
    for (int m = 0; m < 4; ++m)
#pragma unroll
      for (int j = 0; j < 4; ++j)
        res[m][j] = hfp[(b * 64 + m * 16 + g * 4 + j) * kHW];
#pragma unroll
    for (int m = 0; m < 4; ++m) {
      const bf16x8 pA0 = wp[(24 + m * 2 + 0) * 64 + l];
      const bf16x8 pA1 = wp[(24 + m * 2 + 1) * 64 + l];
      f32x4 o =
          __builtin_amdgcn_mfma_f32_16x16x32_bf16(pA0, yS0[b], zz, 0, 0, 0);
      o = __builtin_amdgcn_mfma_f32_16x16x32_bf16(pA1, yS1[b], o, 0, 0, 0);
#pragma unroll
      for (int j = 0; j < 4; ++j) {
        outp[(b * 64 + m * 16 + g * 4 + j) * kHW] =
            fmaf(rv, o[j] + bias_[m][j], res[m][j]);
      }
    }
  }
}

extern "C" void kernel_launch(void* const* d_in, const int* in_sizes, int n_in,
                              void* d_out, int out_size, void* d_ws,
                              size_t ws_size, hipStream_t stream) {
  const float* hf = (const float*)d_in[0];
  const float* Wqkv = (const float*)d_in[1];
  const float* Wproj = (const float*)d_in[2];
  const float* bproj = (const float*)d_in[3];
  const float* rscale = (const float*)d_in[4];
  float* out = (float*)d_out;
  unsigned char* wsc = (unsigned char*)d_ws;

  hipLaunchKernelGGL(pack_weights, dim3(1), dim3(256), 0, stream, Wqkv, Wproj,
                     wsc);

  const int npix = in_sizes[0] / kC;  // 131072
  const int nblocks = npix / 64;      // 2048
  hipLaunchKernelGGL(hfattn_mfma4, dim3(nblocks), dim3(256), 0, stream, hf, wsc,
                     bproj, rscale, out);
}

// Round 7
// 52.525 us; speedup vs baseline: 1.5904x; 1.3541x over previous
//
#include <hip/hip_runtime.h>

// HFOnlyAttn MFMA v5 = v2 champion + epilogue residual reconstructed from Xf
// via shuffles (transient, no VMEM, no added live range) + launch_bounds(256,5).
// qkv^T = Wqkv^T (192x64) @ X^T (64 x px); 4-head 3x3 softmax in-register;
// y -> per-wave LDS relayout -> proj: out^T = Wproj^T @ y^T; residual epilogue.
// mfma_f32_16x16x32_bf16:  A: lane l -> row=l&15, k=(l>>4)*8+{0..7}
//                          B: lane l -> col=l&15, k=(l>>4)*8+{0..7}
//                          C: lane l -> col=l&15, row=(l>>4)*4+reg
// Residual extraction (derived, see round notes): channel b*64+m*16+g*4+j of
// pixel c lives in Xf[b][m>>1], element (g&1)*4+j, on lane ((m&1)*2+(g>>1))*16+c.

typedef __attribute__((ext_vector_type(8))) short bf16x8;
typedef __attribute__((ext_vector_type(4))) float f32x4;

constexpr int kHW = 16384;
constexpr int kC = 192;

__device__ __forceinline__ unsigned short f2bf(float f) {
  unsigned int u = __float_as_uint(f);
  return (unsigned short)((u + 0x7fffu + ((u >> 16) & 1u)) >> 16);  // RNE
}

// kernel0: pack Wqkv^T/Wproj^T A-fragments into ws (24 + 8 frags x 1024B).
__global__ void pack_weights(const float* __restrict__ Wqkv,
                             const float* __restrict__ Wproj,
                             unsigned char* __restrict__ wsc) {
  const int tid = threadIdx.x;
  const int wid = tid >> 6;
  const int l = tid & 63;
  const int c = l & 15;
  const int g = l >> 4;
  for (int f = wid; f < 24; f += 4) {
    const int m = f >> 1, s = f & 1;
    const int row = m * 16 + c;
    const int k0 = s * 32 + g * 8;
    bf16x8 wf;
#pragma unroll
    for (int j = 0; j < 8; ++j) wf[j] = (short)f2bf(Wqkv[(k0 + j) * 192 + row]);
    *(bf16x8*)(wsc + f * 1024 + l * 16) = wf;
  }
  for (int f = wid; f < 8; f += 4) {
    const int m = f >> 1, s = f & 1;
    const int row = m * 16 + c;
    const int k0 = s * 32 + g * 8;
    bf16x8 wf;
#pragma unroll
    for (int j = 0; j < 8; ++j) wf[j] = (short)f2bf(Wproj[(k0 + j) * 64 + row]);
    *(bf16x8*)(wsc + 24576 + f * 1024 + l * 16) = wf;
  }
}

__global__ __launch_bounds__(256, 5) void hfattn_mfma5(
    const float* __restrict__ hf,
    const unsigned char* __restrict__ wfr,  // packed weight frags (32KB)
    const float* __restrict__ bproj,
    const float* __restrict__ rscale,
    float* __restrict__ out) {
  // LDS: y relayout only, 6KB per wave (private to the wave, no barrier).
  __shared__ char smem[24576];

  const int tid = threadIdx.x;
  const int wid = tid >> 6;
  const int l = tid & 63;
  const int c = l & 15;  // MFMA col (pixel slot)
  const int g = l >> 4;  // 4-lane group

  char* const yBase = smem + wid * 6144;
  const f32x4 zz = {0.f, 0.f, 0.f, 0.f};
  const bf16x8* const wp = (const bf16x8*)wfr;

  const int pxB = blockIdx.x * 64 + wid * 16;  // 2048 blocks x 64 px
  const int b8 = pxB >> 14;
  const int blkBase = b8 * (kC * kHW);
  const int hw = (pxB & (kHW - 1)) + c;
  const float* __restrict__ hfp = hf + blkBase + hw;
  float* __restrict__ outp = out + blkBase + hw;

  const float rv = rscale[0];

  // ---------- X fragments from global ----------
  bf16x8 Xf[3][2];
#pragma unroll
  for (int b = 0; b < 3; ++b)
#pragma unroll
    for (int s = 0; s < 2; ++s) {
      const int ch0 = b * 64 + s * 32 + g * 8;
      float xr[8];
#pragma unroll
      for (int j = 0; j < 8; ++j) xr[j] = hfp[(ch0 + j) * kHW];
      bf16x8 xf;
#pragma unroll
      for (int j = 0; j < 8; ++j) xf[j] = (short)f2bf(xr[j]);
      Xf[b][s] = xf;
    }

  // ---------- per-head: q,k -> softmax -> v -> y -> LDS ----------
#pragma unroll 1
  for (int h = 0; h < 4; ++h) {
    const bf16x8 qA0 = wp[(h * 2 + 0) * 64 + l];
    const bf16x8 qA1 = wp[(h * 2 + 1) * 64 + l];
    const bf16x8 kA0 = wp[((4 + h) * 2 + 0) * 64 + l];
    const bf16x8 kA1 = wp[((4 + h) * 2 + 1) * 64 + l];
    f32x4 q[3], k[3];
#pragma unroll
    for (int b = 0; b < 3; ++b) {
      q[b] = __builtin_amdgcn_mfma_f32_16x16x32_bf16(qA0, Xf[b][0], zz, 0, 0, 0);
      q[b] = __builtin_amdgcn_mfma_f32_16x16x32_bf16(qA1, Xf[b][1], q[b], 0, 0, 0);
      k[b] = __builtin_amdgcn_mfma_f32_16x16x32_bf16(kA0, Xf[b][0], zz, 0, 0, 0);
      k[b] = __builtin_amdgcn_mfma_f32_16x16x32_bf16(kA1, Xf[b][1], k[b], 0, 0, 0);
    }
    // scores + softmax (reduce over the 4-lane row-groups)
    float P[3][3];
#pragma unroll
    for (int r1 = 0; r1 < 3; ++r1) {
      float sc[3];
#pragma unroll
      for (int r2 = 0; r2 < 3; ++r2) {
        float d = q[r1][0] * k[r2][0] + q[r1][1] * k[r2][1] +
                  q[r1][2] * k[r2][2] + q[r1][3] * k[r2][3];
        d += __shfl_xor(d, 16);
        d += __shfl_xor(d, 32);
        sc[r2] = d * 0.25f;
      }
      const float mx = fmaxf(sc[0], fmaxf(sc[1], sc[2]));
      const float e0 = __expf(sc[0] - mx);
      const float e1 = __expf(sc[1] - mx);
      const float e2 = __expf(sc[2] - mx);
      const float inv = 1.f / (e0 + e1 + e2);
      P[r1][0] = e0 * inv;
      P[r1][1] = e1 * inv;
      P[r1][2] = e2 * inv;
    }
    // v
    const bf16x8 vA0 = wp[((8 + h) * 2 + 0) * 64 + l];
    const bf16x8 vA1 = wp[((8 + h) * 2 + 1) * 64 + l];
    f32x4 v[3];
#pragma unroll
    for (int b = 0; b < 3; ++b) {
      v[b] = __builtin_amdgcn_mfma_f32_16x16x32_bf16(vA0, Xf[b][0], zz, 0, 0, 0);
      v[b] = __builtin_amdgcn_mfma_f32_16x16x32_bf16(vA1, Xf[b][1], v[b], 0, 0, 0);
    }
    // y = P @ v, write to LDS in proj-B-frag layout.
    const int sp = h >> 1;
    const int gp = (h & 1) * 2 + (g >> 1);
    const int wslot = (gp * 16 + c) * 16 + (g & 1) * 8;
#pragma unroll
    for (int r1 = 0; r1 < 3; ++r1) {
      float y0 = P[r1][0] * v[0][0] + P[r1][1] * v[1][0] + P[r1][2] * v[2][0];
      float y1 = P[r1][0] * v[0][1] + P[r1][1] * v[1][1] + P[r1][2] * v[2][1];
      float y2 = P[r1][0] * v[0][2] + P[r1][1] * v[1][2] + P[r1][2] * v[2][2];
      float y3 = P[r1][0] * v[0][3] + P[r1][1] * v[1][3] + P[r1][2] * v[2][3];
      uint2 pk;
      pk.x = (unsigned)f2bf(y0) | ((unsigned)f2bf(y1) << 16);
      pk.y = (unsigned)f2bf(y2) | ((unsigned)f2bf(y3) << 16);
      *(uint2*)(yBase + (r1 * 2 + sp) * 1024 + wslot) = pk;
    }
  }

  // ---------- epilogue: proj + residual-from-Xf ----------
  float bias_[4][4];
#pragma unroll
  for (int m = 0; m < 4; ++m) {
    const float4 bj = *(const float4*)(bproj + m * 16 + g * 4);
    bias_[m][0] = bj.x;
    bias_[m][1] = bj.y;
    bias_[m][2] = bj.z;
    bias_[m][3] = bj.w;
  }

#pragma unroll
  for (int b = 0; b < 3; ++b) {
    const bf16x8 yB0 = *(bf16x8*)(yBase + (b * 2 + 0) * 1024 + l * 16);
    const bf16x8 yB1 = *(bf16x8*)(yBase + (b * 2 + 1) * 1024 + l * 16);
#pragma unroll
    for (int m = 0; m < 4; ++m) {
      const bf16x8 pA0 = wp[(24 + m * 2 + 0) * 64 + l];
      const bf16x8 pA1 = wp[(24 + m * 2 + 1) * 64 + l];
      f32x4 o = __builtin_amdgcn_mfma_f32_16x16x32_bf16(pA0, yB0, zz, 0, 0, 0);
      o = __builtin_amdgcn_mfma_f32_16x16x32_bf16(pA1, yB1, o, 0, 0, 0);

      // residual from Xf via wave shuffles (all transient)
      union {
        bf16x8 v;
        unsigned u[4];
      } su;
      su.v = Xf[b][m >> 1];
      const int hl = ((m & 1) * 2 + (g >> 1)) * 16 + c;
      const unsigned w0 = (unsigned)__shfl((int)su.u[0], hl, 64);
      const unsigned w1 = (unsigned)__shfl((int)su.u[1], hl, 64);
      const unsigned w2 = (unsigned)__shfl((int)su.u[2], hl, 64);
      const unsigned w3 = (unsigned)__shfl((int)su.u[3], hl, 64);
      const unsigned lo = (g & 1) ? w2 : w0;  // channels j=0,1
      const unsigned hi = (g & 1) ? w3 : w1;  // channels j=2,3
      float res[4];
      res[0] = __uint_as_float(lo << 16);
      res[1] = __uint_as_float(lo & 0xffff0000u);
      res[2] = __uint_as_float(hi << 16);
      res[3] = __uint_as_float(hi & 0xffff0000u);

#pragma unroll
      for (int j = 0; j < 4; ++j) {
        outp[(b * 64 + m * 16 + g * 4 + j) * kHW] =
            fmaf(rv, o[j] + bias_[m][j], res[j]);
      }
    }
  }
}

extern "C" void kernel_launch(void* const* d_in, const int* in_sizes, int n_in,
                              void* d_out, int out_size, void* d_ws,
                              size_t ws_size, hipStream_t stream) {
  const float* hf = (const float*)d_in[0];
  const float* Wqkv = (const float*)d_in[1];
  const float* Wproj = (const float*)d_in[2];
  const float* bproj = (const float*)d_in[3];
  const float* rscale = (const float*)d_in[4];
  float* out = (float*)d_out;
  unsigned char* wsc = (unsigned char*)d_ws;

  hipLaunchKernelGGL(pack_weights, dim3(1), dim3(256), 0, stream, Wqkv, Wproj,
                     wsc);

  const int npix = in_sizes[0] / kC;  // 131072
  const int nblocks = npix / 64;      // 2048
  hipLaunchKernelGGL(hfattn_mfma5, dim3(nblocks), dim3(256), 0, stream, hf, wsc,
                     bproj, rscale, out);
}

// Round 8
// 50.822 us; speedup vs baseline: 1.6437x; 1.0335x over previous
//
#include <hip/hip_runtime.h>

// HFOnlyAttn MFMA v6 = v5 + explicit full-depth X-load staging (48 outstanding
// VMEM ops, sched_barrier-fenced) + launch_bounds(256,4).
// qkv^T = Wqkv^T (192x64) @ X^T (64 x px); 4-head 3x3 softmax in-register;
// y -> per-wave LDS relayout -> proj: out^T = Wproj^T @ y^T; residual from Xf.
// mfma_f32_16x16x32_bf16:  A: lane l -> row=l&15, k=(l>>4)*8+{0..7}
//                          B: lane l -> col=l&15, k=(l>>4)*8+{0..7}
//                          C: lane l -> col=l&15, row=(l>>4)*4+reg
// Residual extraction: channel b*64+m*16+g*4+j of pixel c lives in
// Xf[b][m>>1], element (g&1)*4+j, on lane ((m&1)*2+(g>>1))*16+c.

typedef __attribute__((ext_vector_type(8))) short bf16x8;
typedef __attribute__((ext_vector_type(4))) float f32x4;

constexpr int kHW = 16384;
constexpr int kC = 192;

__device__ __forceinline__ unsigned short f2bf(float f) {
  unsigned int u = __float_as_uint(f);
  return (unsigned short)((u + 0x7fffu + ((u >> 16) & 1u)) >> 16);  // RNE
}

// kernel0: pack Wqkv^T/Wproj^T A-fragments into ws (24 + 8 frags x 1024B).
__global__ void pack_weights(const float* __restrict__ Wqkv,
                             const float* __restrict__ Wproj,
                             unsigned char* __restrict__ wsc) {
  const int tid = threadIdx.x;
  const int wid = tid >> 6;
  const int l = tid & 63;
  const int c = l & 15;
  const int g = l >> 4;
  for (int f = wid; f < 24; f += 4) {
    const int m = f >> 1, s = f & 1;
    const int row = m * 16 + c;
    const int k0 = s * 32 + g * 8;
    bf16x8 wf;
#pragma unroll
    for (int j = 0; j < 8; ++j) wf[j] = (short)f2bf(Wqkv[(k0 + j) * 192 + row]);
    *(bf16x8*)(wsc + f * 1024 + l * 16) = wf;
  }
  for (int f = wid; f < 8; f += 4) {
    const int m = f >> 1, s = f & 1;
    const int row = m * 16 + c;
    const int k0 = s * 32 + g * 8;
    bf16x8 wf;
#pragma unroll
    for (int j = 0; j < 8; ++j) wf[j] = (short)f2bf(Wproj[(k0 + j) * 64 + row]);
    *(bf16x8*)(wsc + 24576 + f * 1024 + l * 16) = wf;
  }
}

__global__ __launch_bounds__(256, 4) void hfattn_mfma6(
    const float* __restrict__ hf,
    const unsigned char* __restrict__ wfr,  // packed weight frags (32KB)
    const float* __restrict__ bproj,
    const float* __restrict__ rscale,
    float* __restrict__ out) {
  // LDS: y relayout only, 6KB per wave (private to the wave, no barrier).
  __shared__ char smem[24576];

  const int tid = threadIdx.x;
  const int wid = tid >> 6;
  const int l = tid & 63;
  const int c = l & 15;  // MFMA col (pixel slot)
  const int g = l >> 4;  // 4-lane group

  char* const yBase = smem + wid * 6144;
  const f32x4 zz = {0.f, 0.f, 0.f, 0.f};
  const bf16x8* const wp = (const bf16x8*)wfr;

  const int pxB = blockIdx.x * 64 + wid * 16;  // 2048 blocks x 64 px
  const int b8 = pxB >> 14;
  const int blkBase = b8 * (kC * kHW);
  const int hw = (pxB & (kHW - 1)) + c;
  const float* __restrict__ hfp = hf + blkBase + hw;
  float* __restrict__ outp = out + blkBase + hw;

  const float rv = rscale[0];

  // ---------- phase 1: issue ALL 48 X loads (deep MLP), fence, convert ----------
  float xr[3][2][8];
#pragma unroll
  for (int b = 0; b < 3; ++b)
#pragma unroll
    for (int s = 0; s < 2; ++s)
#pragma unroll
      for (int j = 0; j < 8; ++j)
        xr[b][s][j] = hfp[(b * 64 + s * 32 + g * 8 + j) * kHW];
  __builtin_amdgcn_sched_barrier(0);  // all 48 loads issue before any convert

  bf16x8 Xf[3][2];
#pragma unroll
  for (int b = 0; b < 3; ++b)
#pragma unroll
    for (int s = 0; s < 2; ++s) {
      bf16x8 xf;
#pragma unroll
      for (int j = 0; j < 8; ++j) xf[j] = (short)f2bf(xr[b][s][j]);
      Xf[b][s] = xf;
    }

  // ---------- per-head: q,k -> softmax -> v -> y -> LDS ----------
#pragma unroll 1
  for (int h = 0; h < 4; ++h) {
    const bf16x8 qA0 = wp[(h * 2 + 0) * 64 + l];
    const bf16x8 qA1 = wp[(h * 2 + 1) * 64 + l];
    const bf16x8 kA0 = wp[((4 + h) * 2 + 0) * 64 + l];
    const bf16x8 kA1 = wp[((4 + h) * 2 + 1) * 64 + l];
    f32x4 q[3], k[3];
#pragma unroll
    for (int b = 0; b < 3; ++b) {
      q[b] = __builtin_amdgcn_mfma_f32_16x16x32_bf16(qA0, Xf[b][0], zz, 0, 0, 0);
      q[b] = __builtin_amdgcn_mfma_f32_16x16x32_bf16(qA1, Xf[b][1], q[b], 0, 0, 0);
      k[b] = __builtin_amdgcn_mfma_f32_16x16x32_bf16(kA0, Xf[b][0], zz, 0, 0, 0);
      k[b] = __builtin_amdgcn_mfma_f32_16x16x32_bf16(kA1, Xf[b][1], k[b], 0, 0, 0);
    }
    // scores + softmax (reduce over the 4-lane row-groups)
    float P[3][3];
#pragma unroll
    for (int r1 = 0; r1 < 3; ++r1) {
      float sc[3];
#pragma unroll
      for (int r2 = 0; r2 < 3; ++r2) {
        float d = q[r1][0] * k[r2][0] + q[r1][1] * k[r2][1] +
                  q[r1][2] * k[r2][2] + q[r1][3] * k[r2][3];
        d += __shfl_xor(d, 16);
        d += __shfl_xor(d, 32);
        sc[r2] = d * 0.25f;
      }
      const float mx = fmaxf(sc[0], fmaxf(sc[1], sc[2]));
      const float e0 = __expf(sc[0] - mx);
      const float e1 = __expf(sc[1] - mx);
      const float e2 = __expf(sc[2] - mx);
      const float inv = 1.f / (e0 + e1 + e2);
      P[r1][0] = e0 * inv;
      P[r1][1] = e1 * inv;
      P[r1][2] = e2 * inv;
    }
    // v
    const bf16x8 vA0 = wp[((8 + h) * 2 + 0) * 64 + l];
    const bf16x8 vA1 = wp[((8 + h) * 2 + 1) * 64 + l];
    f32x4 v[3];
#pragma unroll
    for (int b = 0; b < 3; ++b) {
      v[b] = __builtin_amdgcn_mfma_f32_16x16x32_bf16(vA0, Xf[b][0], zz, 0, 0, 0);
      v[b] = __builtin_amdgcn_mfma_f32_16x16x32_bf16(vA1, Xf[b][1], v[b], 0, 0, 0);
    }
    // y = P @ v, write to LDS in proj-B-frag layout.
    const int sp = h >> 1;
    const int gp = (h & 1) * 2 + (g >> 1);
    const int wslot = (gp * 16 + c) * 16 + (g & 1) * 8;
#pragma unroll
    for (int r1 = 0; r1 < 3; ++r1) {
      float y0 = P[r1][0] * v[0][0] + P[r1][1] * v[1][0] + P[r1][2] * v[2][0];
      float y1 = P[r1][0] * v[0][1] + P[r1][1] * v[1][1] + P[r1][2] * v[2][1];
      float y2 = P[r1][0] * v[0][2] + P[r1][1] * v[1][2] + P[r1][2] * v[2][2];
      float y3 = P[r1][0] * v[0][3] + P[r1][1] * v[1][3] + P[r1][2] * v[2][3];
      uint2 pk;
      pk.x = (unsigned)f2bf(y0) | ((unsigned)f2bf(y1) << 16);
      pk.y = (unsigned)f2bf(y2) | ((unsigned)f2bf(y3) << 16);
      *(uint2*)(yBase + (r1 * 2 + sp) * 1024 + wslot) = pk;
    }
  }

  // ---------- epilogue: proj + residual-from-Xf ----------
  float bias_[4][4];
#pragma unroll
  for (int m = 0; m < 4; ++m) {
    const float4 bj = *(const float4*)(bproj + m * 16 + g * 4);
    bias_[m][0] = bj.x;
    bias_[m][1] = bj.y;
    bias_[m][2] = bj.z;
    bias_[m][3] = bj.w;
  }

#pragma unroll
  for (int b = 0; b < 3; ++b) {
    const bf16x8 yB0 = *(bf16x8*)(yBase + (b * 2 + 0) * 1024 + l * 16);
    const bf16x8 yB1 = *(bf16x8*)(yBase + (b * 2 + 1) * 1024 + l * 16);
#pragma unroll
    for (int m = 0; m < 4; ++m) {
      const bf16x8 pA0 = wp[(24 + m * 2 + 0) * 64 + l];
      const bf16x8 pA1 = wp[(24 + m * 2 + 1) * 64 + l];
      f32x4 o = __builtin_amdgcn_mfma_f32_16x16x32_bf16(pA0, yB0, zz, 0, 0, 0);
      o = __builtin_amdgcn_mfma_f32_16x16x32_bf16(pA1, yB1, o, 0, 0, 0);

      // residual from Xf via wave shuffles (all transient)
      union {
        bf16x8 v;
        unsigned u[4];
      } su;
      su.v = Xf[b][m >> 1];
      const int hl = ((m & 1) * 2 + (g >> 1)) * 16 + c;
      const unsigned w0 = (unsigned)__shfl((int)su.u[0], hl, 64);
      const unsigned w1 = (unsigned)__shfl((int)su.u[1], hl, 64);
      const unsigned w2 = (unsigned)__shfl((int)su.u[2], hl, 64);
      const unsigned w3 = (unsigned)__shfl((int)su.u[3], hl, 64);
      const unsigned lo = (g & 1) ? w2 : w0;  // channels j=0,1
      const unsigned hi = (g & 1) ? w3 : w1;  // channels j=2,3
      float res[4];
      res[0] = __uint_as_float(lo << 16);
      res[1] = __uint_as_float(lo & 0xffff0000u);
      res[2] = __uint_as_float(hi << 16);
      res[3] = __uint_as_float(hi & 0xffff0000u);

#pragma unroll
      for (int j = 0; j < 4; ++j) {
        outp[(b * 64 + m * 16 + g * 4 + j) * kHW] =
            fmaf(rv, o[j] + bias_[m][j], res[j]);
      }
    }
  }
}

extern "C" void kernel_launch(void* const* d_in, const int* in_sizes, int n_in,
                              void* d_out, int out_size, void* d_ws,
                              size_t ws_size, hipStream_t stream) {
  const float* hf = (const float*)d_in[0];
  const float* Wqkv = (const float*)d_in[1];
  const float* Wproj = (const float*)d_in[2];
  const float* bproj = (const float*)d_in[3];
  const float* rscale = (const float*)d_in[4];
  float* out = (float*)d_out;
  unsigned char* wsc = (unsigned char*)d_ws;

  hipLaunchKernelGGL(pack_weights, dim3(1), dim3(256), 0, stream, Wqkv, Wproj,
                     wsc);

  const int npix = in_sizes[0] / kC;  // 131072
  const int nblocks = npix / 64;      // 2048
  hipLaunchKernelGGL(hfattn_mfma6, dim3(nblocks), dim3(256), 0, stream, hf, wsc,
                     bproj, rscale, out);
}

// Round 9
// 49.003 us; speedup vs baseline: 1.7047x; 1.0371x over previous
//
#include <hip/hip_runtime.h>

// HFOnlyAttn MFMA v7 = v6 with __launch_bounds__(256,6): 6 blocks/CU
// (LDS 6x24576=147KB of 160KB; VGPR cap 85). Occupancy is the binding
// constraint per round-8 arithmetic (issue work ~9us vs 50us wall).
// qkv^T = Wqkv^T (192x64) @ X^T (64 x px); 4-head 3x3 softmax in-register;
// y -> per-wave LDS relayout -> proj: out^T = Wproj^T @ y^T; residual from Xf.
// mfma_f32_16x16x32_bf16:  A: lane l -> row=l&15, k=(l>>4)*8+{0..7}
//                          B: lane l -> col=l&15, k=(l>>4)*8+{0..7}
//                          C: lane l -> col=l&15, row=(l>>4)*4+reg
// Residual extraction: channel b*64+m*16+g*4+j of pixel c lives in
// Xf[b][m>>1], element (g&1)*4+j, on lane ((m&1)*2+(g>>1))*16+c.

typedef __attribute__((ext_vector_type(8))) short bf16x8;
typedef __attribute__((ext_vector_type(4))) float f32x4;

constexpr int kHW = 16384;
constexpr int kC = 192;

__device__ __forceinline__ unsigned short f2bf(float f) {
  unsigned int u = __float_as_uint(f);
  return (unsigned short)((u + 0x7fffu + ((u >> 16) & 1u)) >> 16);  // RNE
}

// kernel0: pack Wqkv^T/Wproj^T A-fragments into ws (24 + 8 frags x 1024B).
__global__ void pack_weights(const float* __restrict__ Wqkv,
                             const float* __restrict__ Wproj,
                             unsigned char* __restrict__ wsc) {
  const int tid = threadIdx.x;
  const int wid = tid >> 6;
  const int l = tid & 63;
  const int c = l & 15;
  const int g = l >> 4;
  for (int f = wid; f < 24; f += 4) {
    const int m = f >> 1, s = f & 1;
    const int row = m * 16 + c;
    const int k0 = s * 32 + g * 8;
    bf16x8 wf;
#pragma unroll
    for (int j = 0; j < 8; ++j) wf[j] = (short)f2bf(Wqkv[(k0 + j) * 192 + row]);
    *(bf16x8*)(wsc + f * 1024 + l * 16) = wf;
  }
  for (int f = wid; f < 8; f += 4) {
    const int m = f >> 1, s = f & 1;
    const int row = m * 16 + c;
    const int k0 = s * 32 + g * 8;
    bf16x8 wf;
#pragma unroll
    for (int j = 0; j < 8; ++j) wf[j] = (short)f2bf(Wproj[(k0 + j) * 64 + row]);
    *(bf16x8*)(wsc + 24576 + f * 1024 + l * 16) = wf;
  }
}

__global__ __launch_bounds__(256, 6) void hfattn_mfma7(
    const float* __restrict__ hf,
    const unsigned char* __restrict__ wfr,  // packed weight frags (32KB)
    const float* __restrict__ bproj,
    const float* __restrict__ rscale,
    float* __restrict__ out) {
  // LDS: y relayout only, 6KB per wave (private to the wave, no barrier).
  __shared__ char smem[24576];

  const int tid = threadIdx.x;
  const int wid = tid >> 6;
  const int l = tid & 63;
  const int c = l & 15;  // MFMA col (pixel slot)
  const int g = l >> 4;  // 4-lane group

  char* const yBase = smem + wid * 6144;
  const f32x4 zz = {0.f, 0.f, 0.f, 0.f};
  const bf16x8* const wp = (const bf16x8*)wfr;

  const int pxB = blockIdx.x * 64 + wid * 16;  // 2048 blocks x 64 px
  const int b8 = pxB >> 14;
  const int blkBase = b8 * (kC * kHW);
  const int hw = (pxB & (kHW - 1)) + c;
  const float* __restrict__ hfp = hf + blkBase + hw;
  float* __restrict__ outp = out + blkBase + hw;

  const float rv = rscale[0];

  // ---------- phase 1: issue ALL 48 X loads, fence, convert ----------
  float xr[3][2][8];
#pragma unroll
  for (int b = 0; b < 3; ++b)
#pragma unroll
    for (int s = 0; s < 2; ++s)
#pragma unroll
      for (int j = 0; j < 8; ++j)
        xr[b][s][j] = hfp[(b * 64 + s * 32 + g * 8 + j) * kHW];
  __builtin_amdgcn_sched_barrier(0);  // all 48 loads issue before any convert

  bf16x8 Xf[3][2];
#pragma unroll
  for (int b = 0; b < 3; ++b)
#pragma unroll
    for (int s = 0; s < 2; ++s) {
      bf16x8 xf;
#pragma unroll
      for (int j = 0; j < 8; ++j) xf[j] = (short)f2bf(xr[b][s][j]);
      Xf[b][s] = xf;
    }

  // ---------- per-head: q,k -> softmax -> v -> y -> LDS ----------
#pragma unroll 1
  for (int h = 0; h < 4; ++h) {
    const bf16x8 qA0 = wp[(h * 2 + 0) * 64 + l];
    const bf16x8 qA1 = wp[(h * 2 + 1) * 64 + l];
    const bf16x8 kA0 = wp[((4 + h) * 2 + 0) * 64 + l];
    const bf16x8 kA1 = wp[((4 + h) * 2 + 1) * 64 + l];
    f32x4 q[3], k[3];
#pragma unroll
    for (int b = 0; b < 3; ++b) {
      q[b] = __builtin_amdgcn_mfma_f32_16x16x32_bf16(qA0, Xf[b][0], zz, 0, 0, 0);
      q[b] = __builtin_amdgcn_mfma_f32_16x16x32_bf16(qA1, Xf[b][1], q[b], 0, 0, 0);
      k[b] = __builtin_amdgcn_mfma_f32_16x16x32_bf16(kA0, Xf[b][0], zz, 0, 0, 0);
      k[b] = __builtin_amdgcn_mfma_f32_16x16x32_bf16(kA1, Xf[b][1], k[b], 0, 0, 0);
    }
    // scores + softmax (reduce over the 4-lane row-groups)
    float P[3][3];
#pragma unroll
    for (int r1 = 0; r1 < 3; ++r1) {
      float sc[3];
#pragma unroll
      for (int r2 = 0; r2 < 3; ++r2) {
        float d = q[r1][0] * k[r2][0] + q[r1][1] * k[r2][1] +
                  q[r1][2] * k[r2][2] + q[r1][3] * k[r2][3];
        d += __shfl_xor(d, 16);
        d += __shfl_xor(d, 32);
        sc[r2] = d * 0.25f;
      }
      const float mx = fmaxf(sc[0], fmaxf(sc[1], sc[2]));
      const float e0 = __expf(sc[0] - mx);
      const float e1 = __expf(sc[1] - mx);
      const float e2 = __expf(sc[2] - mx);
      const float inv = 1.f / (e0 + e1 + e2);
      P[r1][0] = e0 * inv;
      P[r1][1] = e1 * inv;
      P[r1][2] = e2 * inv;
    }
    // v
    const bf16x8 vA0 = wp[((8 + h) * 2 + 0) * 64 + l];
    const bf16x8 vA1 = wp[((8 + h) * 2 + 1) * 64 + l];
    f32x4 v[3];
#pragma unroll
    for (int b = 0; b < 3; ++b) {
      v[b] = __builtin_amdgcn_mfma_f32_16x16x32_bf16(vA0, Xf[b][0], zz, 0, 0, 0);
      v[b] = __builtin_amdgcn_mfma_f32_16x16x32_bf16(vA1, Xf[b][1], v[b], 0, 0, 0);
    }
    // y = P @ v, write to LDS in proj-B-frag layout.
    const int sp = h >> 1;
    const int gp = (h & 1) * 2 + (g >> 1);
    const int wslot = (gp * 16 + c) * 16 + (g & 1) * 8;
#pragma unroll
    for (int r1 = 0; r1 < 3; ++r1) {
      float y0 = P[r1][0] * v[0][0] + P[r1][1] * v[1][0] + P[r1][2] * v[2][0];
      float y1 = P[r1][0] * v[0][1] + P[r1][1] * v[1][1] + P[r1][2] * v[2][1];
      float y2 = P[r1][0] * v[0][2] + P[r1][1] * v[1][2] + P[r1][2] * v[2][2];
      float y3 = P[r1][0] * v[0][3] + P[r1][1] * v[1][3] + P[r1][2] * v[2][3];
      uint2 pk;
      pk.x = (unsigned)f2bf(y0) | ((unsigned)f2bf(y1) << 16);
      pk.y = (unsigned)f2bf(y2) | ((unsigned)f2bf(y3) << 16);
      *(uint2*)(yBase + (r1 * 2 + sp) * 1024 + wslot) = pk;
    }
  }

  // ---------- epilogue: proj + residual-from-Xf ----------
  float bias_[4][4];
#pragma unroll
  for (int m = 0; m < 4; ++m) {
    const float4 bj = *(const float4*)(bproj + m * 16 + g * 4);
    bias_[m][0] = bj.x;
    bias_[m][1] = bj.y;
    bias_[m][2] = bj.z;
    bias_[m][3] = bj.w;
  }

#pragma unroll
  for (int b = 0; b < 3; ++b) {
    const bf16x8 yB0 = *(bf16x8*)(yBase + (b * 2 + 0) * 1024 + l * 16);
    const bf16x8 yB1 = *(bf16x8*)(yBase + (b * 2 + 1) * 1024 + l * 16);
#pragma unroll
    for (int m = 0; m < 4; ++m) {
      const bf16x8 pA0 = wp[(24 + m * 2 + 0) * 64 + l];
      const bf16x8 pA1 = wp[(24 + m * 2 + 1) * 64 + l];
      f32x4 o = __builtin_amdgcn_mfma_f32_16x16x32_bf16(pA0, yB0, zz, 0, 0, 0);
      o = __builtin_amdgcn_mfma_f32_16x16x32_bf16(pA1, yB1, o, 0, 0, 0);

      // residual from Xf via wave shuffles (all transient)
      union {
        bf16x8 v;
        unsigned u[4];
      } su;
      su.v = Xf[b][m >> 1];
      const int hl = ((m & 1) * 2 + (g >> 1)) * 16 + c;
      const unsigned w0 = (unsigned)__shfl((int)su.u[0], hl, 64);
      const unsigned w1 = (unsigned)__shfl((int)su.u[1], hl, 64);
      const unsigned w2 = (unsigned)__shfl((int)su.u[2], hl, 64);
      const unsigned w3 = (unsigned)__shfl((int)su.u[3], hl, 64);
      const unsigned lo = (g & 1) ? w2 : w0;  // channels j=0,1
      const unsigned hi = (g & 1) ? w3 : w1;  // channels j=2,3
      float res[4];
      res[0] = __uint_as_float(lo << 16);
      res[1] = __uint_as_float(lo & 0xffff0000u);
      res[2] = __uint_as_float(hi << 16);
      res[3] = __uint_as_float(hi & 0xffff0000u);

#pragma unroll
      for (int j = 0; j < 4; ++j) {
        outp[(b * 64 + m * 16 + g * 4 + j) * kHW] =
            fmaf(rv, o[j] + bias_[m][j], res[j]);
      }
    }
  }
}

extern "C" void kernel_launch(void* const* d_in, const int* in_sizes, int n_in,
                              void* d_out, int out_size, void* d_ws,
                              size_t ws_size, hipStream_t stream) {
  const float* hf = (const float*)d_in[0];
  const float* Wqkv = (const float*)d_in[1];
  const float* Wproj = (const float*)d_in[2];
  const float* bproj = (const float*)d_in[3];
  const float* rscale = (const float*)d_in[4];
  float* out = (float*)d_out;
  unsigned char* wsc = (unsigned char*)d_ws;

  hipLaunchKernelGGL(pack_weights, dim3(1), dim3(256), 0, stream, Wqkv, Wproj,
                     wsc);

  const int npix = in_sizes[0] / kC;  // 131072
  const int nblocks = npix / 64;      // 2048
  hipLaunchKernelGGL(hfattn_mfma7, dim3(nblocks), dim3(256), 0, stream, hf, wsc,
                     bproj, rscale, out);
}